// Round 2
// baseline (851.876 us; speedup 1.0000x reference)
//
#include <hip/hip_runtime.h>
#include <math.h>

#define NTOK   16384
#define DIM    4096
#define NEXP   256
#define NGRP   8
#define TOPKG  4
#define TOPK   8

// ---------------- GEMM: logits[T,E] = X[T,D] * W[E,D]^T (fp32) ----------------
// 128x128 block tile, 8x8 micro-tile, 256 threads, double-buffered LDS,
// register prefetch of the next global tile. 256 blocks -> 1 per CU.
#define BM 128
#define BN 128
#define BK 16
#define LDA (BM + 4)
#define LDB (BN + 4)

__global__ __launch_bounds__(256, 1) void gate_gemm(const float* __restrict__ X,
                                                    const float* __restrict__ W,
                                                    float* __restrict__ L) {
    __shared__ float As[2][BK][LDA];   // 2*16*132*4 = 16.9 KB
    __shared__ float Bs[2][BK][LDB];

    const int t  = threadIdx.x;
    const int bm = blockIdx.y * BM;    // token block (0..127)
    const int bn = blockIdx.x * BN;    // expert block (0..1)

    // staging: thread t loads row sm, float4-quads sq and sq+1 (of 4 per BK row)
    const int sm = t >> 1;             // 0..127
    const int sq = (t & 1) * 2;        // 0 or 2
    const float* xa = X + (size_t)(bm + sm) * DIM + sq * 4;
    const float* wb = W + (size_t)(bn + sm) * DIM + sq * 4;

    // compute: thread (tx,ty) owns rows ty*8..+7, cols tx*8..+7
    const int tx = t & 15;
    const int ty = t >> 4;

    float4 pa0, pa1, pb0, pb1;

    // ---- load tile 0 into regs, stage to LDS buf 0 ----
    pa0 = *(const float4*)(xa);
    pa1 = *(const float4*)(xa + 4);
    pb0 = *(const float4*)(wb);
    pb1 = *(const float4*)(wb + 4);
#pragma unroll
    for (int j = 0; j < 4; ++j) {
        As[0][sq * 4 + j][sm]       = (&pa0.x)[j];
        As[0][(sq + 1) * 4 + j][sm] = (&pa1.x)[j];
        Bs[0][sq * 4 + j][sm]       = (&pb0.x)[j];
        Bs[0][(sq + 1) * 4 + j][sm] = (&pb1.x)[j];
    }
    __syncthreads();

    float acc[8][8] = {};
    int p = 0;

    for (int k0 = BK; k0 <= DIM; k0 += BK) {
        const bool has_next = (k0 < DIM);
        if (has_next) {
            pa0 = *(const float4*)(xa + k0);
            pa1 = *(const float4*)(xa + k0 + 4);
            pb0 = *(const float4*)(wb + k0);
            pb1 = *(const float4*)(wb + k0 + 4);
        }

#pragma unroll
        for (int k = 0; k < BK; ++k) {
            float4 a0 = *(const float4*)&As[p][k][ty * 8];
            float4 a1 = *(const float4*)&As[p][k][ty * 8 + 4];
            float4 b0 = *(const float4*)&Bs[p][k][tx * 8];
            float4 b1 = *(const float4*)&Bs[p][k][tx * 8 + 4];
            const float ar[8] = {a0.x, a0.y, a0.z, a0.w, a1.x, a1.y, a1.z, a1.w};
            const float br[8] = {b0.x, b0.y, b0.z, b0.w, b1.x, b1.y, b1.z, b1.w};
#pragma unroll
            for (int i = 0; i < 8; ++i)
#pragma unroll
                for (int j = 0; j < 8; ++j)
                    acc[i][j] = fmaf(ar[i], br[j], acc[i][j]);
        }

        if (has_next) {
            const int q = p ^ 1;
#pragma unroll
            for (int j = 0; j < 4; ++j) {
                As[q][sq * 4 + j][sm]       = (&pa0.x)[j];
                As[q][(sq + 1) * 4 + j][sm] = (&pa1.x)[j];
                Bs[q][sq * 4 + j][sm]       = (&pb0.x)[j];
                Bs[q][(sq + 1) * 4 + j][sm] = (&pb1.x)[j];
            }
            __syncthreads();
            p = q;
        }
    }

#pragma unroll
    for (int i = 0; i < 8; ++i) {
        float* dst = &L[(size_t)(bm + ty * 8 + i) * NEXP + bn + tx * 8];
        *(float4*)(dst)     = make_float4(acc[i][0], acc[i][1], acc[i][2], acc[i][3]);
        *(float4*)(dst + 4) = make_float4(acc[i][4], acc[i][5], acc[i][6], acc[i][7]);
    }
}

// ---------------- Routing: one wave (64 lanes) per token ----------------
// lane holds experts 4*lane .. 4*lane+3; group = lane>>3 (8 lanes/group of 32)
__global__ __launch_bounds__(256) void gate_route(const float* __restrict__ L,
                                                  float* __restrict__ outw,
                                                  float* __restrict__ outi) {
    const int lane = threadIdx.x & 63;
    const int tok  = (blockIdx.x * blockDim.x + threadIdx.x) >> 6;
    if (tok >= NTOK) return;

    const float* row = L + (size_t)tok * NEXP;
    float4 v = *(const float4*)(row + lane * 4);
    float l[4] = {v.x, v.y, v.z, v.w};

    // wave-wide max logit
    float lmax = fmaxf(fmaxf(l[0], l[1]), fmaxf(l[2], l[3]));
    float m = lmax;
#pragma unroll
    for (int o = 32; o; o >>= 1) m = fmaxf(m, __shfl_xor(m, o));

    // softmax denominator over ALL 256 experts
    float s = __expf(l[0] - m) + __expf(l[1] - m) + __expf(l[2] - m) + __expf(l[3] - m);
#pragma unroll
    for (int o = 32; o; o >>= 1) s += __shfl_xor(s, o);

    // per-group max logit (monotone proxy for max softmax score)
    float gm = lmax;
#pragma unroll
    for (int o = 4; o; o >>= 1) gm = fmaxf(gm, __shfl_xor(gm, o));

    // rank my group among the 8 group maxes (ties -> lower group index wins)
    const int g = lane >> 3;
    int rank = 0;
#pragma unroll
    for (int gg = 0; gg < 8; ++gg) {
        float vg = __shfl(gm, gg * 8);
        rank += (vg > gm) || (vg == gm && gg < g);
    }
    const bool allowed = rank < TOPKG;

    float mv[4];
#pragma unroll
    for (int j = 0; j < 4; ++j) mv[j] = allowed ? l[j] : -INFINITY;

    float wsel = 0.0f;
    int   isel = 0;

    for (int k = 0; k < TOPK; ++k) {
        // local argmax among this lane's 4 (tie -> lower index via strict >)
        float bv = mv[0];
        int   bi = lane * 4;
        if (mv[1] > bv) { bv = mv[1]; bi = lane * 4 + 1; }
        if (mv[2] > bv) { bv = mv[2]; bi = lane * 4 + 2; }
        if (mv[3] > bv) { bv = mv[3]; bi = lane * 4 + 3; }
        // wave argmax with (value desc, index asc) lexicographic order
#pragma unroll
        for (int o = 32; o; o >>= 1) {
            float ov = __shfl_xor(bv, o);
            int   oi = __shfl_xor(bi, o);
            if (ov > bv || (ov == bv && oi < bi)) { bv = ov; bi = oi; }
        }
        if (lane == k) { wsel = __expf(bv - m) / s; isel = bi; }
        if ((bi >> 2) == lane) mv[bi & 3] = -INFINITY;  // remove selected
    }

    if (lane < TOPK) {
        outw[(size_t)tok * TOPK + lane] = wsel;
        outi[(size_t)tok * TOPK + lane] = (float)isel;
    }
}

extern "C" void kernel_launch(void* const* d_in, const int* in_sizes, int n_in,
                              void* d_out, int out_size, void* d_ws, size_t ws_size,
                              hipStream_t stream) {
    const float* x = (const float*)d_in[0];   // [16384, 4096]
    const float* w = (const float*)d_in[1];   // [256, 4096]
    float* logits  = (float*)d_ws;            // [16384, 256] = 16 MB
    float* outw    = (float*)d_out;                       // [16384, 8] weights
    float* outi    = (float*)d_out + (size_t)NTOK * TOPK; // [16384, 8] idx (as float)

    dim3 ggrid(NEXP / BN, NTOK / BM);   // (2, 128) = 256 blocks
    gate_gemm<<<ggrid, 256, 0, stream>>>(x, w, logits);

    int rblocks = (NTOK * 64) / 256;    // 4096 blocks
    gate_route<<<rblocks, 256, 0, stream>>>(logits, outw, outi);
}